// Round 1
// baseline (107.700 us; speedup 1.0000x reference)
//
#include <hip/hip_runtime.h>

// S4D kernel: K[h,l] = 2 * Re( sum_n Ct[h,n] * z[h,n]^l )
//   z  = exp(dtA),  dtA = (-exp(log_A_real) + i*A_imag) * exp(log_dt[h])
//   Ct = (C_real + i*C_imag) * (z - 1) / A
//
// Strategy: geometric recurrence in l instead of per-element transcendentals.
// One block (256 threads) per h. Thread t owns l = t + 256*j (j=0..15) so the
// 16 stores per thread are fully coalesced across the block. Per-thread state
// s_n starts at Ct_n * z_n^t (computed once with fast-intrinsic exp/sincos,
// phase reduced in double for accuracy) and advances by w_n = z_n^256 each j.

#define N2   32
#define LLEN 4096
#define BLK  256
#define CL   (LLEN / BLK)   // 16 outputs per thread
#define NCH  8              // n-chunk size (register pressure control)

__global__ __launch_bounds__(BLK, 4) void s4d_kernel(
    const float* __restrict__ log_dt,
    const float* __restrict__ C_real,
    const float* __restrict__ C_imag,
    const float* __restrict__ log_A_real,
    const float* __restrict__ A_imag,
    float* __restrict__ out)
{
    const int h = blockIdx.x;
    const int t = threadIdx.x;

    const float dt = __expf(log_dt[h]);

    float acc[CL];
#pragma unroll
    for (int j = 0; j < CL; ++j) acc[j] = 0.0f;

    const float* __restrict__ lar = log_A_real + h * N2;
    const float* __restrict__ aim = A_imag     + h * N2;
    const float* __restrict__ cre = C_real     + h * N2;
    const float* __restrict__ cim = C_imag     + h * N2;

    for (int n0 = 0; n0 < N2; n0 += NCH) {
        float sr[NCH], si[NCH], wr[NCH], wi[NCH];

#pragma unroll
        for (int k = 0; k < NCH; ++k) {
            const int n = n0 + k;
            const float aR = -__expf(lar[n]);   // Re(A) = -exp(log_A_real)
            const float aI = aim[n];            // Im(A)
            const float dR = aR * dt;           // Re(dtA)
            const float dI = aI * dt;           // Im(dtA)

            // z = exp(dtA)
            const float e1 = __expf(dR);
            const float zr = e1 * __cosf(dI);
            const float zi = e1 * __sinf(dI);

            // q = (z - 1) / A   (complex divide via conj(A)/|A|^2)
            const float inv = 1.0f / (aR * aR + aI * aI);
            const float nr  = zr - 1.0f;
            const float ni  = zi;
            const float qr  = (nr * aR + ni * aI) * inv;
            const float qi  = (ni * aR - nr * aI) * inv;

            // Ct = (C_real + i C_imag) * q
            const float c_r = cre[n], c_i = cim[n];
            const float Ctr = c_r * qr - c_i * qi;
            const float Cti = c_r * qi + c_i * qr;

            // phase per step, in revolutions; double keeps t*theta accurate
            // (max ~6400 revolutions -> fp32 alone would give ~1.5e-3 rad err)
            const double trev = (double)dI * 0.15915494309189535; // 1/(2*pi)

            // start state: s = Ct * z^t
            double ph = trev * (double)t;
            ph -= floor(ph);
            const float ang = (float)ph * 6.283185307179586f;
            const float er  = __expf(dR * (float)t);
            const float pr  = er * __cosf(ang);
            const float pim = er * __sinf(ang);
            sr[k] = Ctr * pr - Cti * pim;
            si[k] = Ctr * pim + Cti * pr;

            // recurrence multiplier: w = z^BLK
            double ph2 = trev * (double)BLK;
            ph2 -= floor(ph2);
            const float ang2 = (float)ph2 * 6.283185307179586f;
            const float ew   = __expf(dR * (float)BLK);
            wr[k] = ew * __cosf(ang2);
            wi[k] = ew * __sinf(ang2);
        }

        // main loop: 16 steps x 8 independent complex chains
#pragma unroll
        for (int j = 0; j < CL; ++j) {
            float sum = 0.0f;
#pragma unroll
            for (int k = 0; k < NCH; ++k) {
                sum += sr[k];
                const float tr = sr[k] * wr[k] - si[k] * wi[k];
                const float ti = sr[k] * wi[k] + si[k] * wr[k];
                sr[k] = tr;
                si[k] = ti;
            }
            acc[j] += sum;
        }
    }

    float* __restrict__ o = out + (size_t)h * LLEN + t;
#pragma unroll
    for (int j = 0; j < CL; ++j) o[j * BLK] = 2.0f * acc[j];
}

extern "C" void kernel_launch(void* const* d_in, const int* in_sizes, int n_in,
                              void* d_out, int out_size, void* d_ws, size_t ws_size,
                              hipStream_t stream) {
    const float* log_dt     = (const float*)d_in[0];
    const float* C_real     = (const float*)d_in[1];
    const float* C_imag     = (const float*)d_in[2];
    const float* log_A_real = (const float*)d_in[3];
    const float* A_imag     = (const float*)d_in[4];
    float* out = (float*)d_out;

    const int H = in_sizes[0];  // 1024; grid = one block per h
    s4d_kernel<<<dim3(H), dim3(BLK), 0, stream>>>(
        log_dt, C_real, C_imag, log_A_real, A_imag, out);
}

// Round 2
// 84.703 us; speedup vs baseline: 1.2715x; 1.2715x over previous
//
#include <hip/hip_runtime.h>

// S4D kernel: K[h,l] = 2 * Re( sum_n Ct[h,n] * z[h,n]^l )
//   z  = exp(dtA),  dtA = (-exp(log_A_real) + i*A_imag) * exp(log_dt[h])
//   Ct = (C_real + i*C_imag) * (z - 1) / A
//
// R2 structure:
//  - one 256-thread block per h; thread t owns l = t + 256*j (j=0..15),
//    stores fully coalesced.
//  - t-independent per-(h,n) setup (z, q, Ct, w=z^256, dR*log2e, trev) is
//    computed ONCE by lanes 0..31 into LDS (was: redundantly by all 256
//    threads -> ~200 wasted transcendental/fp64 instrs per thread).
//  - per-thread start state s = Ct * z^t uses double-reduced phase
//    (revolutions), fed straight to v_sin/v_cos via __builtin_amdgcn_sinf
//    (HW takes revolutions - skips the radians scaling mul).
//  - main recurrence is packed fp32 (ext_vector_type(2)) so the backend can
//    emit v_pk_mul/fma/add_f32: 3 packed ops per (n, j) step.

#define N2   32
#define LLEN 4096
#define BLK  256
#define CL   (LLEN / BLK)   // 16 outputs per thread
#define NCH  8              // n-chunk size (register pressure control)

typedef float v2f __attribute__((ext_vector_type(2)));

__global__ __launch_bounds__(BLK, 4) void s4d_kernel(
    const float* __restrict__ log_dt,
    const float* __restrict__ C_real,
    const float* __restrict__ C_imag,
    const float* __restrict__ log_A_real,
    const float* __restrict__ A_imag,
    float* __restrict__ out)
{
    const int h = blockIdx.x;
    const int t = threadIdx.x;

    __shared__ float4  sA[N2];     // {Ctr, Cti, wr, wi}
    __shared__ double  sTrev[N2];  // dI / (2*pi), exact-ish step phase in revolutions
    __shared__ float   sDr[N2];    // dR * log2(e)  (for exp2-based magnitude)

    // ---- per-(h,n) setup: lanes 0..31 only ----
    if (t < N2) {
        const int n = t;
        const float dt = __expf(log_dt[h]);
        const float aR = -__expf(log_A_real[h * N2 + n]);
        const float aI = A_imag[h * N2 + n];
        const float dR = aR * dt;
        const float dI = aI * dt;

        const double trev = (double)dI * 0.15915494309189535; // radians -> revolutions

        // z = exp(dR + i*dI)
        double phz = trev; phz -= floor(phz);
        const float e1 = __expf(dR);
        const float zr = e1 * __builtin_amdgcn_cosf((float)phz);
        const float zi = e1 * __builtin_amdgcn_sinf((float)phz);

        // q = (z - 1) / A
        const float inv = 1.0f / (aR * aR + aI * aI);
        const float nr  = zr - 1.0f;
        const float ni  = zi;
        const float qr  = (nr * aR + ni * aI) * inv;
        const float qi  = (ni * aR - nr * aI) * inv;

        // Ct = (C_real + i*C_imag) * q
        const float c_r = C_real[h * N2 + n], c_i = C_imag[h * N2 + n];
        const float Ctr = c_r * qr - c_i * qi;
        const float Cti = c_r * qi + c_i * qr;

        // w = z^BLK
        double ph2 = trev * (double)BLK; ph2 -= floor(ph2);
        const float ew = __expf(dR * (float)BLK);
        const float wr = ew * __builtin_amdgcn_cosf((float)ph2);
        const float wi = ew * __builtin_amdgcn_sinf((float)ph2);

        sA[n]    = make_float4(Ctr, Cti, wr, wi);
        sTrev[n] = trev;
        sDr[n]   = dR * 1.4426950408889634f;
    }
    __syncthreads();

    v2f acc[CL];
#pragma unroll
    for (int j = 0; j < CL; ++j) acc[j] = (v2f){0.0f, 0.0f};

    const float  tf = (float)t;
    const double td = (double)t;

    for (int n0 = 0; n0 < N2; n0 += NCH) {
        v2f s[NCH], w[NCH], wc[NCH];

#pragma unroll
        for (int k = 0; k < NCH; ++k) {
            const int n = n0 + k;
            const float4 A = sA[n];          // broadcast LDS read (conflict-free)
            w[k]  = (v2f){ A.z,  A.w };
            wc[k] = (v2f){-A.w,  A.z };

            // s = Ct * z^t
            const float er = __builtin_amdgcn_exp2f(sDr[n] * tf);
            double p = sTrev[n] * td; p -= floor(p);
            const float ph01 = (float)p;                       // revolutions in [0,1)
            const float pr  = er * __builtin_amdgcn_cosf(ph01);
            const float pim = er * __builtin_amdgcn_sinf(ph01);
            s[k] = (v2f){ A.x * pr - A.y * pim,
                          A.x * pim + A.y * pr };
        }

        // main loop: 16 steps x 8 independent complex chains, packed fp32
#pragma unroll
        for (int j = 0; j < CL; ++j) {
#pragma unroll
            for (int k = 0; k < NCH; ++k) {
                acc[j] += s[k];                                      // v_pk_add_f32
                const v2f sx = __builtin_shufflevector(s[k], s[k], 0, 0);
                const v2f sy = __builtin_shufflevector(s[k], s[k], 1, 1);
                s[k] = sx * w[k] + sy * wc[k];                       // v_pk_mul + v_pk_fma
            }
        }
    }

    float* __restrict__ o = out + (size_t)h * LLEN + t;
#pragma unroll
    for (int j = 0; j < CL; ++j) o[j * BLK] = 2.0f * acc[j].x;
}

extern "C" void kernel_launch(void* const* d_in, const int* in_sizes, int n_in,
                              void* d_out, int out_size, void* d_ws, size_t ws_size,
                              hipStream_t stream) {
    const float* log_dt     = (const float*)d_in[0];
    const float* C_real     = (const float*)d_in[1];
    const float* C_imag     = (const float*)d_in[2];
    const float* log_A_real = (const float*)d_in[3];
    const float* A_imag     = (const float*)d_in[4];
    float* out = (float*)d_out;

    const int H = in_sizes[0];  // 1024; one block per h
    s4d_kernel<<<dim3(H), dim3(BLK), 0, stream>>>(
        log_dt, C_real, C_imag, log_A_real, A_imag, out);
}

// Round 3
// 80.136 us; speedup vs baseline: 1.3440x; 1.0570x over previous
//
#include <hip/hip_runtime.h>

// S4D kernel: K[h,l] = 2 * Re( sum_n Ct[h,n] * z[h,n]^l )
//   z  = exp(dtA),  dtA = (-exp(log_A_real) + i*A_imag) * exp(log_dt[h])
//   Ct = (C_real + i*C_imag) * (z - 1) / A
//
// R3 structure:
//  - one 256-thread block per h; thread t owns l = t + 256*j (j=0..15),
//    stores fully coalesced.
//  - t-independent per-(h,n) setup in LDS (computed by lanes 0..31).
//  - KEY CHANGE: we only need Re(s). x_j = Re(Ct z^t w^j) satisfies the
//    real 2nd-order recurrence  x_{j+1} = 2Re(w) x_j - |w|^2 x_{j-1}
//    (characteristic roots w, conj(w), both |.|<1 -> stable). This is
//    elementwise -> two n's packed per v2f: exactly 3 packed VALU ops
//    (v_pk_add + v_pk_mul + v_pk_fma) per (n-pair, j). No complex
//    cross-terms, no shufflevector broadcasts the backend might scalarize.
//  - per-thread phase uses a double-float (hi,lo) split of the step phase
//    (revolutions), precomputed in double once per (h,n): per-thread path is
//    pure fp32 (twoprod fma + fract), no fp64 in the hot 256-thread code.

#define N2    32
#define NPAIR (N2 / 2)
#define LLEN  4096
#define BLK   256
#define CL    (LLEN / BLK)  // 16 outputs per thread
#define PCH   4             // pairs per chunk (8 n's) - register pressure control

typedef float v2f __attribute__((ext_vector_type(2)));

__global__ __launch_bounds__(BLK, 4) void s4d_kernel(
    const float* __restrict__ log_dt,
    const float* __restrict__ C_real,
    const float* __restrict__ C_imag,
    const float* __restrict__ log_A_real,
    const float* __restrict__ A_imag,
    float* __restrict__ out)
{
    const int h = blockIdx.x;
    const int t = threadIdx.x;

    __shared__ v2f   sCt[N2];      // {Ctr, Cti}
    __shared__ v2f   sW[N2];       // {Re(w), Im(w)}, w = z^256
    __shared__ float sInvR2[N2];   // 1 / |w|^2
    __shared__ float s2A[N2];      // 2*Re(w)    (read as packed pairs)
    __shared__ float sMR2[N2];     // -|w|^2     (read as packed pairs)
    __shared__ float sDrL2[N2];    // Re(dtA) * log2(e)
    __shared__ float sTh[N2];      // hi(step phase, revolutions)
    __shared__ float sTl[N2];      // lo(step phase, revolutions)

    // ---- per-(h,n) setup: lanes 0..31 only (fp64 allowed here, cold) ----
    if (t < N2) {
        const int n = t;
        const float dt = __expf(log_dt[h]);
        const float aR = -__expf(log_A_real[h * N2 + n]);
        const float aI = A_imag[h * N2 + n];
        const float dR = aR * dt;

        // step phase in revolutions, computed in double then split hi/lo
        const double trev = (double)aI * (double)dt * 0.15915494309189535;
        const float  th   = (float)trev;
        const float  tl   = (float)(trev - (double)th);

        // z = exp(dR + i*2*pi*trev)
        double pz = trev; pz -= floor(pz);
        const float e1 = __expf(dR);
        const float zr = e1 * __builtin_amdgcn_cosf((float)pz);
        const float zi = e1 * __builtin_amdgcn_sinf((float)pz);

        // q = (z - 1) / A
        const float inv = 1.0f / (aR * aR + aI * aI);
        const float nr  = zr - 1.0f;
        const float qr  = (nr * aR + zi * aI) * inv;
        const float qi  = (zi * aR - nr * aI) * inv;

        // Ct = (C_real + i*C_imag) * q
        const float c_r = C_real[h * N2 + n], c_i = C_imag[h * N2 + n];
        const float Ctr = c_r * qr - c_i * qi;
        const float Cti = c_r * qi + c_i * qr;

        // w = z^256
        double p256 = trev * 256.0; p256 -= floor(p256);
        const float ew = __expf(dR * 256.0f);
        const float wa = ew * __builtin_amdgcn_cosf((float)p256);
        const float wb = ew * __builtin_amdgcn_sinf((float)p256);
        const float r2 = ew * ew;

        sCt[n]    = (v2f){Ctr, Cti};
        sW[n]     = (v2f){wa, wb};
        sInvR2[n] = 1.0f / r2;
        s2A[n]    = 2.0f * wa;
        sMR2[n]   = -r2;
        sDrL2[n]  = dR * 1.4426950408889634f;
        sTh[n]    = th;
        sTl[n]    = tl;
    }
    __syncthreads();

    v2f acc[CL];
#pragma unroll
    for (int j = 0; j < CL; ++j) acc[j] = (v2f){0.0f, 0.0f};

    const float tf = (float)t;
    const v2f* __restrict__ p2A  = (const v2f*)s2A;
    const v2f* __restrict__ pMR2 = (const v2f*)sMR2;

    for (int p0 = 0; p0 < NPAIR; p0 += PCH) {
        v2f x[PCH], xm[PCH], c2a[PCH], cmr[PCH];

#pragma unroll
        for (int k = 0; k < PCH; ++k) {
            const int pair = p0 + k;
            c2a[k] = p2A[pair];
            cmr[k] = pMR2[pair];

#pragma unroll
            for (int e = 0; e < 2; ++e) {
                const int n = 2 * pair + e;
                // |z|^t
                const float er = __builtin_amdgcn_exp2f(sDrL2[n] * tf);
                // phase(t) = fract(t * trev), double-float accuracy in fp32:
                const float th = sTh[n], tl = sTl[n];
                const float p  = th * tf;
                const float perr = __builtin_fmaf(th, tf, -p);   // twoprod err
                float f = __builtin_amdgcn_fractf(p);
                f += __builtin_fmaf(tl, tf, perr);
                const float c = __builtin_amdgcn_cosf(f);
                const float s = __builtin_amdgcn_sinf(f);

                const v2f Ct = sCt[n];
                const v2f w  = sW[n];
                const float x0 = er * (Ct.x * c - Ct.y * s);   // Re(Ct z^t)
                const float y0 = er * (Ct.x * s + Ct.y * c);   // Im(Ct z^t)
                // x_{-1} = Re(Ct z^t / w) = (x0*Re(w) + y0*Im(w)) / |w|^2
                const float xm1 = (x0 * w.x + y0 * w.y) * sInvR2[n];
                if (e == 0) { x[k].x = x0; xm[k].x = xm1; }
                else        { x[k].y = x0; xm[k].y = xm1; }
            }
        }

        // main loop: 16 steps x PCH packed 2nd-order recurrences
#pragma unroll
        for (int j = 0; j < CL; ++j) {
#pragma unroll
            for (int k = 0; k < PCH; ++k) {
                acc[j] += x[k];                      // v_pk_add_f32
                const v2f tmp = cmr[k] * xm[k];      // v_pk_mul_f32
                xm[k] = x[k];
                x[k]  = c2a[k] * x[k] + tmp;         // v_pk_fma_f32
            }
        }
    }

    float* __restrict__ o = out + (size_t)h * LLEN + t;
#pragma unroll
    for (int j = 0; j < CL; ++j) o[j * BLK] = 2.0f * (acc[j].x + acc[j].y);
}

extern "C" void kernel_launch(void* const* d_in, const int* in_sizes, int n_in,
                              void* d_out, int out_size, void* d_ws, size_t ws_size,
                              hipStream_t stream) {
    const float* log_dt     = (const float*)d_in[0];
    const float* C_real     = (const float*)d_in[1];
    const float* C_imag     = (const float*)d_in[2];
    const float* log_A_real = (const float*)d_in[3];
    const float* A_imag     = (const float*)d_in[4];
    float* out = (float*)d_out;

    const int H = in_sizes[0];  // 1024; one block per h
    s4d_kernel<<<dim3(H), dim3(BLK), 0, stream>>>(
        log_dt, C_real, C_imag, log_A_real, A_imag, out);
}